// Round 3
// baseline (206.014 us; speedup 1.0000x reference)
//
#include <hip/hip_runtime.h>

// YOLOv1 loss: batch x 7 x 7 x 30 fp32 inputs (y_trues, y_preds) -> scalar.
// ~193 MB input. History:
//   R0 (AoS, 1 atomic/block):        78 us, invariant to HBM-cold vs L3-warm.
//   R1 (LDS-staged coalesced loads): 74.5 us, unchanged -> NOT transaction-bound.
//   R2 (two-stage reduce via d_ws):  container died twice -- suspected
//       unguarded d_ws write (ws possibly null/small). This round: same
//       experiment with a ws_size guard + atomic fallback.
// Theory under test: grid=3136 same-address device atomicAdds serialize at
// ~24 ns each (cross-XCD line bounce) -> 75 us critical path. Replacing them
// with contention-free partial stores + tiny reduce kernel should expose the
// true streaming time (~30 us).

#define SS 49      // S*S
#define DD 30      // C + 5*B
#define BLOCK 256
#define CPB 256            // cells per block
#define TILE_F (CPB * DD)  // 7680 floats per array per tile (30720 B)

// Async, direct global->LDS copy, 16B per lane. Dest must be linear
// (wave-uniform base + lane*16) -- our staging loop is exactly that.
__device__ __forceinline__ void g2l16(const float* g, float* l) {
    __builtin_amdgcn_global_load_lds(
        (const __attribute__((address_space(1))) void*)g,
        (__attribute__((address_space(3))) void*)l,
        16, 0, 0);
}

__device__ __forceinline__ float iou_yolo(const float b1[4], const float b2[4]) {
    const float EPS = 1e-6f;
    float b1x1 = b1[0] - b1[2] * 0.5f, b1y1 = b1[1] - b1[3] * 0.5f;
    float b1x2 = b1[0] + b1[2] * 0.5f, b1y2 = b1[1] + b1[3] * 0.5f;
    float b2x1 = b2[0] - b2[2] * 0.5f, b2y1 = b2[1] - b2[3] * 0.5f;
    float b2x2 = b2[0] + b2[2] * 0.5f, b2y2 = b2[1] + b2[3] * 0.5f;
    float iw = fmaxf(fminf(b1x2, b2x2) - fmaxf(b1x1, b2x1), 0.0f);
    float ih = fmaxf(fminf(b1y2, b2y2) - fmaxf(b1y1, b2y1), 0.0f);
    float inter = iw * ih;
    float a1 = fabsf((b1x2 - b1x1) * (b1y2 - b1y1));
    float a2 = fabsf((b2x2 - b2x1) * (b2y2 - b2y1));
    return inter / (a1 + a2 - inter + EPS);
}

// Core per-cell loss from LDS-staged rows; shared by both reduction paths.
__device__ __forceinline__ float cell_loss(const float* __restrict__ yt,
                                           const float* __restrict__ yp) {
    const float LAMBDA_COORD = 5.0f;
    const float LAMBDA_NOOBJ = 0.5f;
    const float EPS = 1e-6f;

    float obj = (yt[4] == 1.0f) ? 1.0f : 0.0f;
    float noobj = 1.0f - obj;

    float tb[4]  = {yt[0], yt[1], yt[2], yt[3]};
    float pb1[4] = {yp[0], yp[1], yp[2], yp[3]};
    float pb2[4] = {yp[5], yp[6], yp[7], yp[8]};
    float iou1 = iou_yolo(tb, pb1);
    float iou2 = iou_yolo(tb, pb2);
    bool best1 = iou1 > iou2;

    float bh0 = best1 ? yp[0] : yp[5];
    float bh1 = best1 ? yp[1] : yp[6];
    float bh2 = best1 ? yp[2] : yp[7];
    float bh3 = best1 ? yp[3] : yp[8];
    float conf_hat       = best1 ? yp[4] : yp[9];
    float other_conf_hat = best1 ? yp[9] : yp[4];

    float dx = yt[0] - bh0, dy = yt[1] - bh1;
    float xy = dx * dx + dy * dy;

    float sw = sqrtf(yt[2]) - sqrtf(fabsf(bh2 + EPS));
    float sh = sqrtf(yt[3]) - sqrtf(fabsf(bh3 + EPS));
    float wh = sw * sw + sh * sh;

    float dc = yt[4] - conf_hat;
    float obj_conf = dc * dc;

    float noobj_in_obj = LAMBDA_NOOBJ * other_conf_hat * other_conf_hat;

    float d4 = yt[4] - yp[4];
    float d9 = yt[4] - yp[9];
    float noobj_cells = LAMBDA_NOOBJ * (d4 * d4 + d9 * d9);

    float cls = 0.0f;
#pragma unroll
    for (int k = 10; k < DD; ++k) {
        float d = yt[k] - yp[k];
        cls += d * d;
    }

    return obj * (LAMBDA_COORD * (xy + wh) + obj_conf + noobj_in_obj + cls)
         + noobj * noobj_cells;
}

// USE_WS=1: write per-block partial to partials[blockIdx.x] (contention-free).
// USE_WS=0: atomicAdd(out) fallback (R1 behavior, known-correct).
template <int USE_WS>
__global__ __launch_bounds__(BLOCK)
void yolo_loss_kernel(const float* __restrict__ yt_g,
                      const float* __restrict__ yp_g,
                      float* __restrict__ sink,   // partials (USE_WS) or out
                      int ncells, float inv_batch) {
    __shared__ __align__(16) float lt[TILE_F];
    __shared__ __align__(16) float lp[TILE_F];

    const int tid = threadIdx.x;
    const int base_cell = blockIdx.x * CPB;
    const int nc = min(CPB, ncells - base_cell);
    const int nf = nc * DD;
    const int nf4 = nf >> 2;
    const size_t base_f = (size_t)base_cell * DD;

    const float* gt = yt_g + base_f;
    const float* gp = yp_g + base_f;

    // Coalesced staging: lane i of each wave copies 16B at a linear offset.
    for (int j = tid; j < nf4; j += BLOCK) {
        g2l16(gt + 4 * j, &lt[4 * j]);
        g2l16(gp + 4 * j, &lp[4 * j]);
    }
    for (int j = (nf4 << 2) + tid; j < nf; j += BLOCK) {  // tail, dormant here
        lt[j] = gt[j];
        lp[j] = gp[j];
    }
    __syncthreads();  // drains vmcnt (incl. global_load_lds)

    float per_cell = 0.0f;
    if (tid < nc) per_cell = cell_loss(&lt[tid * DD], &lp[tid * DD]);

#pragma unroll
    for (int off = 32; off > 0; off >>= 1)
        per_cell += __shfl_down(per_cell, off, 64);

    __shared__ float smem[BLOCK / 64];
    int lane = threadIdx.x & 63;
    int wave = threadIdx.x >> 6;
    if (lane == 0) smem[wave] = per_cell;
    __syncthreads();
    if (threadIdx.x == 0) {
        float s = smem[0] + smem[1] + smem[2] + smem[3];
        if (USE_WS) sink[blockIdx.x] = s;
        else        atomicAdd(sink, s * inv_batch);
    }
}

// Second stage: one block sums the per-block partials and writes the scalar.
__global__ __launch_bounds__(256)
void reduce_kernel(const float* __restrict__ partials, float* __restrict__ out,
                   int n, float inv_batch) {
    float s = 0.0f;
    for (int i = threadIdx.x; i < n; i += 256) s += partials[i];
#pragma unroll
    for (int off = 32; off > 0; off >>= 1)
        s += __shfl_down(s, off, 64);
    __shared__ float sm[4];
    int lane = threadIdx.x & 63;
    int wave = threadIdx.x >> 6;
    if (lane == 0) sm[wave] = s;
    __syncthreads();
    if (threadIdx.x == 0)
        out[0] = (sm[0] + sm[1] + sm[2] + sm[3]) * inv_batch;
}

extern "C" void kernel_launch(void* const* d_in, const int* in_sizes, int n_in,
                              void* d_out, int out_size, void* d_ws, size_t ws_size,
                              hipStream_t stream) {
    const float* yt = (const float*)d_in[0];
    const float* yp = (const float*)d_in[1];
    float* out = (float*)d_out;
    float* ws = (float*)d_ws;

    int total = in_sizes[0];          // batch * S*S * D
    int ncells = total / DD;          // batch * 49
    int batch = ncells / SS;
    float inv_batch = 1.0f / (float)batch;

    int grid = (ncells + CPB - 1) / CPB;

    if (ws != nullptr && ws_size >= (size_t)grid * sizeof(float)) {
        // Contention-free path: partials to workspace, then 1-block reduce.
        yolo_loss_kernel<1><<<grid, BLOCK, 0, stream>>>(yt, yp, ws, ncells,
                                                        inv_batch);
        reduce_kernel<<<1, 256, 0, stream>>>(ws, out, grid, inv_batch);
    } else {
        // Fallback: R1 atomic path (d_out is poisoned each launch -> memset).
        hipMemsetAsync(out, 0, sizeof(float), stream);
        yolo_loss_kernel<0><<<grid, BLOCK, 0, stream>>>(yt, yp, out, ncells,
                                                        inv_batch);
    }
}